// Round 1
// baseline (12022.782 us; speedup 1.0000x reference)
//
#include <hip/hip_runtime.h>

#define NTH 256
#define SPB 4            // samples per block
#define W66 66
#define PIX36 36
#define NPOS 18          // kx in 0..5, ky in 0..2
#define FEAT 2376        // 66*36
#define TT 256
#define NSAMP 16384

__constant__ float COS6[6] = {1.f, 0.5f, -0.5f, -1.f, -0.5f, 0.5f};
__constant__ float SIN6[6] = {0.f, 0.8660254037844386468f, 0.8660254037844386468f,
                              0.f, -0.8660254037844386468f, -0.8660254037844386468f};

__device__ __forceinline__ float gelu_f(float v) {
    return 0.5f * v * (1.f + erff(v * 0.70710678118654752440f));
}

// repack spectral weights into pack[L][p][i][o][{re,im}], p = kx*3+ky, kx 0..5
extern "C" __global__ void repack_kernel(
    const float* __restrict__ w1r0, const float* __restrict__ w1i0,
    const float* __restrict__ w2r0, const float* __restrict__ w2i0,
    const float* __restrict__ w1r1, const float* __restrict__ w1i1,
    const float* __restrict__ w2r1, const float* __restrict__ w2i1,
    float* __restrict__ pack)
{
    int e = blockIdx.x * blockDim.x + threadIdx.x;
    const int TOT = 2 * NPOS * W66 * W66;
    if (e >= TOT) return;
    int L = e / (NPOS * W66 * W66);
    int r = e % (NPOS * W66 * W66);
    int p = r / (W66 * W66);
    int io = r % (W66 * W66);
    int i = io / W66, o = io % W66;
    int kx = p / 3, ky = p % 3;
    const float *wr, *wi;
    int kxw;
    if (L == 0) { if (kx < 3) { wr = w1r0; wi = w1i0; kxw = kx; } else { wr = w2r0; wi = w2i0; kxw = kx - 3; } }
    else        { if (kx < 3) { wr = w1r1; wi = w1i1; kxw = kx; } else { wr = w2r1; wi = w2i1; kxw = kx - 3; } }
    int src = ((i * W66 + o) * 3 + kxw) * 3 + ky;
    pack[(size_t)e * 2 + 0] = wr[src];
    pack[(size_t)e * 2 + 1] = wi[src];
}

extern "C" __global__ void __launch_bounds__(NTH, 1)
fno_kernel(const float* __restrict__ X, const float* __restrict__ p_w,
           const float* __restrict__ p_b, const float* __restrict__ pack,
           const float* __restrict__ m0aw, const float* __restrict__ m0ab,
           const float* __restrict__ m0bw, const float* __restrict__ m0bb,
           const float* __restrict__ m1aw, const float* __restrict__ m1ab,
           const float* __restrict__ m1bw, const float* __restrict__ m1bb,
           const float* __restrict__ w0w, const float* __restrict__ w0b,
           const float* __restrict__ w1w, const float* __restrict__ w1b,
           const float* __restrict__ gwi, const float* __restrict__ gbi,
           float* __restrict__ gi0out)
{
    extern __shared__ float sm[];
    float* A    = sm;                    // [s][pix][w]  h / skip (9504)
    float* Bb   = A + SPB * FEAT;        // [s][j][w] xft -> [s][pix][o] spatial (9504)
    float* Cc   = Bb + SPB * FEAT;       // [s][j][o] oft -> [s][pix][o] t (9504)
    float* Ft   = Cc + SPB * FEAT;       // F[36 rows][36 pix] forward DFT (1296)
    float* Gt   = Ft + 1296;             // G[36 pix][36 j] inverse (1296)
    float* Fsum = Gt + 1296;             // 36
    float* mv   = Fsum + 36;             // 264
    float* rv   = mv + SPB * W66;        // 264

    const int tid = threadIdx.x;
    const int n0 = blockIdx.x * SPB;

    // ---- build DFT tables (exact values on the 6-point unit circle) ----
    for (int e = tid; e < 1296; e += NTH) {
        int row = e / 36, col = e % 36;
        {   // F[row=(p,c)][pix]: R = cos, I = -sin of 2*pi*(kx*px+ky*py)/6
            int p = row >> 1, cp = row & 1;
            int kx = p / 3, ky = p % 3;
            int px = col / 6, py = col % 6;
            int m6 = (kx * px + ky * py) % 6;
            Ft[e] = cp ? -SIN6[m6] : COS6[m6];
        }
        {   // G[pix=row][j=col]: c_ky*(cos, -sin), c_0=1/36, c_{1,2}=1/18 (c2r drops Im of ky=0)
            int pj = col >> 1, cj = col & 1;
            int kx = pj / 3, ky = pj % 3;
            int px = row / 6, py = row % 6;
            int m6 = (kx * px + ky * py) % 6;
            float ck = (ky == 0) ? (1.f / 36.f) : (1.f / 18.f);
            Gt[e] = cj ? -ck * SIN6[m6] : ck * COS6[m6];
        }
    }
    __syncthreads();
    if (tid < 36) {
        float s = 0.f;
        for (int k = 0; k < 36; ++k) s += Ft[tid * 36 + k];
        Fsum[tid] = s;
    }
    // ---- embed: h = [x, gx, gy] @ p_w + p_b ----
    for (int e = tid; e < SPB * FEAT; e += NTH) {
        int s = e & 3, r = e >> 2;
        int w = r % W66, pix = r / W66;
        int px = pix / 6, py = pix % 6;
        float xv = X[(size_t)(n0 + s) * 36 + pix] + 0.01f;
        A[(s * PIX36 + pix) * W66 + w] =
            xv * p_w[w] + (px * 0.2f) * p_w[66 + w] + (py * 0.2f) * p_w[132 + w] + p_b[w];
    }
    __syncthreads();

    for (int L = 0; L < 2; ++L) {
        const float* maw = L ? m1aw : m0aw;
        const float* mab = L ? m1ab : m0ab;
        const float* mbw = L ? m1bw : m0bw;
        const float* mbb = L ? m1bb : m0bb;
        const float* skw = L ? w1w : w0w;
        const float* skb = L ? w1b : w0b;
        const float2* packF2 = ((const float2*)pack) + (size_t)L * NPOS * W66 * W66;

        // ---- instance-norm stats of A ----
        for (int c = tid; c < SPB * W66; c += NTH) {
            int s = c & 3, ch = c >> 2;
            float smm = 0.f, sq = 0.f;
            #pragma unroll
            for (int pix = 0; pix < 36; ++pix) {
                float v = A[(s * PIX36 + pix) * W66 + ch];
                smm += v; sq = fmaf(v, v, sq);
            }
            float m = smm * (1.f / 36.f);
            float var = sq * (1.f / 36.f) - m * m;
            mv[c] = m; rv[c] = rsqrtf(var + 1e-5f);
        }
        __syncthreads();

        // ---- forward DFT (normalization folded in): A -> Bb [s][j][w] ----
        for (int c = tid; c < SPB * W66; c += NTH) {
            int s = c & 3, w = c >> 2;
            float ar[36];
            #pragma unroll
            for (int pix = 0; pix < 36; ++pix) ar[pix] = A[(s * PIX36 + pix) * W66 + w];
            float m = mv[c], rs = rv[c];
            #pragma unroll 1
            for (int p = 0; p < NPOS; ++p) {
                const float* fR = Ft + (2 * p) * 36;
                const float* fI = fR + 36;
                float s0 = 0.f, s1 = 0.f, t0 = 0.f, t1 = 0.f;
                #pragma unroll
                for (int k = 0; k < 36; k += 2) {
                    s0 = fmaf(ar[k], fR[k], s0);
                    s1 = fmaf(ar[k + 1], fR[k + 1], s1);
                    t0 = fmaf(ar[k], fI[k], t0);
                    t1 = fmaf(ar[k + 1], fI[k + 1], t1);
                }
                Bb[(s * 36 + 2 * p) * W66 + w]     = rs * ((s0 + s1) - m * Fsum[2 * p]);
                Bb[(s * 36 + 2 * p + 1) * W66 + w] = rs * ((t0 + t1) - m * Fsum[2 * p + 1]);
            }
        }
        __syncthreads();

        // ---- per-position complex channel mix: Bb -> Cc [s][j][o] ----
        for (int c = tid; c < SPB * W66; c += NTH) {
            int s = c & 3, o = c >> 2;
            #pragma unroll 1
            for (int p = 0; p < NPOS; ++p) {
                const float* bR = Bb + (s * 36 + 2 * p) * W66;
                const float* bI = bR + W66;
                const float2* wp = packF2 + (size_t)(p * W66) * W66 + o;
                float ar0 = 0.f, ai0 = 0.f, ar1 = 0.f, ai1 = 0.f;
                #pragma unroll 1
                for (int i = 0; i < W66; i += 2) {
                    float xr0 = bR[i], xi0 = bI[i];
                    float2 wv0 = wp[(size_t)i * W66];
                    ar0 = fmaf(xr0, wv0.x, ar0); ar0 = fmaf(xi0, -wv0.y, ar0);
                    ai0 = fmaf(xr0, wv0.y, ai0); ai0 = fmaf(xi0, wv0.x, ai0);
                    float xr1 = bR[i + 1], xi1 = bI[i + 1];
                    float2 wv1 = wp[(size_t)(i + 1) * W66];
                    ar1 = fmaf(xr1, wv1.x, ar1); ar1 = fmaf(xi1, -wv1.y, ar1);
                    ai1 = fmaf(xr1, wv1.y, ai1); ai1 = fmaf(xi1, wv1.x, ai1);
                }
                Cc[(s * 36 + 2 * p) * W66 + o]     = ar0 + ar1;
                Cc[(s * 36 + 2 * p + 1) * W66 + o] = ai0 + ai1;
            }
        }
        __syncthreads();

        // ---- inverse DFT: Cc -> Bb [s][pix][o] ----
        for (int c = tid; c < SPB * W66; c += NTH) {
            int s = c & 3, o = c >> 2;
            float oft[36];
            #pragma unroll
            for (int jj = 0; jj < 36; ++jj) oft[jj] = Cc[(s * 36 + jj) * W66 + o];
            #pragma unroll 1
            for (int pix = 0; pix < PIX36; ++pix) {
                const float* gr = Gt + pix * 36;
                float a0 = 0.f, a1 = 0.f, a2 = 0.f, a3 = 0.f;
                #pragma unroll
                for (int jj = 0; jj < 36; jj += 4) {
                    a0 = fmaf(gr[jj], oft[jj], a0);
                    a1 = fmaf(gr[jj + 1], oft[jj + 1], a1);
                    a2 = fmaf(gr[jj + 2], oft[jj + 2], a2);
                    a3 = fmaf(gr[jj + 3], oft[jj + 3], a3);
                }
                Bb[(s * PIX36 + pix) * W66 + o] = (a0 + a1) + (a2 + a3);
            }
        }
        __syncthreads();

        // ---- instance-norm of spectral output (stats + in-place) ----
        for (int c = tid; c < SPB * W66; c += NTH) {
            int s = c & 3, ch = c >> 2;
            float smm = 0.f, sq = 0.f;
            #pragma unroll
            for (int pix = 0; pix < 36; ++pix) {
                float v = Bb[(s * PIX36 + pix) * W66 + ch];
                smm += v; sq = fmaf(v, v, sq);
            }
            float m = smm * (1.f / 36.f);
            float var = sq * (1.f / 36.f) - m * m;
            mv[c] = m; rv[c] = rsqrtf(var + 1e-5f);
        }
        __syncthreads();
        for (int e = tid; e < SPB * FEAT; e += NTH) {
            int s = e & 3, r = e >> 2;
            int ch = r % W66, pix = r / W66;
            int cidx = (ch << 2) | s;
            int idx = (s * PIX36 + pix) * W66 + ch;
            Bb[idx] = (Bb[idx] - mv[cidx]) * rv[cidx];
        }
        __syncthreads();

        // ---- MLP conv1: Bb -> Cc (t = gelu(Wa x + ba)) ----
        for (int c = tid; c < SPB * W66; c += NTH) {
            int s = c & 3, o = c >> 2;
            float acc[36];
            float bias = mab[o];
            #pragma unroll
            for (int pix = 0; pix < 36; ++pix) acc[pix] = bias;
            #pragma unroll 1
            for (int i = 0; i < W66; ++i) {
                float wv = maw[o * W66 + i];
                const float* brow = Bb + s * FEAT + i;
                #pragma unroll
                for (int pix = 0; pix < 36; ++pix) acc[pix] = fmaf(wv, brow[pix * W66], acc[pix]);
            }
            #pragma unroll
            for (int pix = 0; pix < 36; ++pix) Cc[(s * PIX36 + pix) * W66 + o] = gelu_f(acc[pix]);
        }
        __syncthreads();

        // ---- MLP conv2 + skip conv + gelu -> A ----
        {
            float out0[36], out1[36];
            auto mlp2 = [&](int c, float* ov) {
                int s = c & 3, o = c >> 2;
                float by = mbb[o], bs2 = skb[o];
                float sk[36];
                #pragma unroll
                for (int pix = 0; pix < 36; ++pix) { ov[pix] = by; sk[pix] = bs2; }
                #pragma unroll 1
                for (int i = 0; i < W66; ++i) {
                    float wy = mbw[o * W66 + i];
                    float wsk = skw[o * W66 + i];
                    const float* trow = Cc + s * FEAT + i;
                    const float* arow = A + s * FEAT + i;
                    #pragma unroll
                    for (int pix = 0; pix < 36; ++pix) {
                        ov[pix] = fmaf(wy, trow[pix * W66], ov[pix]);
                        sk[pix] = fmaf(wsk, arow[pix * W66], sk[pix]);
                    }
                }
                #pragma unroll
                for (int pix = 0; pix < 36; ++pix) ov[pix] = gelu_f(ov[pix] + sk[pix]);
            };
            mlp2(tid, out0);
            if (tid < SPB * W66 - NTH) mlp2(tid + NTH, out1);
            __syncthreads();
            {
                int s = tid & 3, o = tid >> 2;
                #pragma unroll
                for (int pix = 0; pix < 36; ++pix) A[(s * PIX36 + pix) * W66 + o] = out0[pix];
                if (tid < SPB * W66 - NTH) {
                    int c2 = tid + NTH, s2 = c2 & 3, o2 = c2 >> 2;
                    #pragma unroll
                    for (int pix = 0; pix < 36; ++pix) A[(s2 * PIX36 + pix) * W66 + o2] = out1[pix];
                }
            }
            __syncthreads();
        }
    }

    // ---- epilogue: gi0 = feats @ Wi0^T + bi0 (feat index = w*36 + pix) ----
    for (int c = tid; c < SPB * 48; c += NTH) {
        int s = c & 3, g = c >> 2;
        const float* wrow = gwi + (size_t)g * FEAT;
        float a0 = 0.f, a1 = 0.f, a2 = 0.f, a3 = 0.f;
        #pragma unroll 1
        for (int w = 0; w < W66; ++w) {
            const float* arow = A + s * FEAT + w;
            const float* wr = wrow + w * 36;
            #pragma unroll
            for (int pix = 0; pix < 36; pix += 4) {
                float4 wq = *(const float4*)(wr + pix);
                a0 = fmaf(arow[(pix + 0) * W66], wq.x, a0);
                a1 = fmaf(arow[(pix + 1) * W66], wq.y, a1);
                a2 = fmaf(arow[(pix + 2) * W66], wq.z, a2);
                a3 = fmaf(arow[(pix + 3) * W66], wq.w, a3);
            }
        }
        gi0out[(size_t)(n0 + s) * 48 + g] = ((a0 + a1) + (a2 + a3)) + gbi[g];
    }
}

// fused GRU0 + GRU1 + output linear; one block per batch element, one wave.
extern "C" __global__ void __launch_bounds__(64, 1)
gru_kernel(const float* __restrict__ gi0, const float* __restrict__ wh0,
           const float* __restrict__ bh0, const float* __restrict__ wi1,
           const float* __restrict__ wh1, const float* __restrict__ bi1,
           const float* __restrict__ bh1, const float* __restrict__ outw,
           const float* __restrict__ outb, float* __restrict__ y)
{
    int b = blockIdx.x;
    int g = threadIdx.x;
    int gw = (g < 48) ? g : 0;
    float rwh0[16], rwi1[16], rwh1[16];
    #pragma unroll
    for (int j = 0; j < 16; ++j) {
        rwh0[j] = wh0[gw * 16 + j];
        rwi1[j] = wi1[gw * 16 + j];
        rwh1[j] = wh1[gw * 16 + j];
    }
    float vbh0 = bh0[gw], vbi1 = bi1[gw], vbh1 = bh1[gw];
    float vow = (g < 16) ? outw[g] : 0.f;
    float ob = outb[0];
    float h0 = 0.f, h1 = 0.f;
    int base = b * TT;
    int j = g & 15;
    float cur = (g < 48) ? gi0[(size_t)base * 48 + g] : 0.f;
    for (int t = 0; t < TT; ++t) {
        int tn = (t + 1 < TT) ? t + 1 : t;
        float nxt = (g < 48) ? gi0[((size_t)base + tn) * 48 + g] : 0.f;
        // layer 0: gh0 = Wh0 h0 + bh0
        float gh0 = vbh0;
        #pragma unroll
        for (int k = 0; k < 16; ++k) gh0 = fmaf(rwh0[k], __shfl(h0, k), gh0);
        float gir = __shfl(cur, j), giz = __shfl(cur, 16 + j), gin = __shfl(cur, 32 + j);
        float ghr = __shfl(gh0, j), ghz = __shfl(gh0, 16 + j), ghn = __shfl(gh0, 32 + j);
        float r = 1.f / (1.f + expf(-(gir + ghr)));
        float z = 1.f / (1.f + expf(-(giz + ghz)));
        float n = tanhf(gin + r * ghn);
        h0 = (1.f - z) * n + z * h0;
        // layer 1
        float gi1 = vbi1, gh1 = vbh1;
        #pragma unroll
        for (int k = 0; k < 16; ++k) {
            gi1 = fmaf(rwi1[k], __shfl(h0, k), gi1);
            gh1 = fmaf(rwh1[k], __shfl(h1, k), gh1);
        }
        float air = __shfl(gi1, j) + __shfl(gh1, j);
        float aiz = __shfl(gi1, 16 + j) + __shfl(gh1, 16 + j);
        float r1 = 1.f / (1.f + expf(-air));
        float z1 = 1.f / (1.f + expf(-aiz));
        float n1 = tanhf(__shfl(gi1, 32 + j) + r1 * __shfl(gh1, 32 + j));
        h1 = (1.f - z1) * n1 + z1 * h1;
        // output projection
        float v = h1 * vow;
        #pragma unroll
        for (int off = 32; off; off >>= 1) v += __shfl_xor(v, off);
        if (g == 0) y[base + t] = v + ob;
        cur = nxt;
    }
}

extern "C" void kernel_launch(void* const* d_in, const int* in_sizes, int n_in,
                              void* d_out, int out_size, void* d_ws, size_t ws_size,
                              hipStream_t stream) {
    const float* X    = (const float*)d_in[0];
    const float* p_w  = (const float*)d_in[1];
    const float* p_b  = (const float*)d_in[2];
    const float* c0w1r = (const float*)d_in[3];
    const float* c0w1i = (const float*)d_in[4];
    const float* c0w2r = (const float*)d_in[5];
    const float* c0w2i = (const float*)d_in[6];
    const float* c1w1r = (const float*)d_in[7];
    const float* c1w1i = (const float*)d_in[8];
    const float* c1w2r = (const float*)d_in[9];
    const float* c1w2i = (const float*)d_in[10];
    const float* m0aw = (const float*)d_in[11];
    const float* m0ab = (const float*)d_in[12];
    const float* m0bw = (const float*)d_in[13];
    const float* m0bb = (const float*)d_in[14];
    const float* m1aw = (const float*)d_in[15];
    const float* m1ab = (const float*)d_in[16];
    const float* m1bw = (const float*)d_in[17];
    const float* m1bb = (const float*)d_in[18];
    const float* w0w  = (const float*)d_in[19];
    const float* w0b  = (const float*)d_in[20];
    const float* w1w  = (const float*)d_in[21];
    const float* w1b  = (const float*)d_in[22];
    const float* g0wi = (const float*)d_in[23];
    const float* g0wh = (const float*)d_in[24];
    const float* g0bi = (const float*)d_in[25];
    const float* g0bh = (const float*)d_in[26];
    const float* g1wi = (const float*)d_in[27];
    const float* g1wh = (const float*)d_in[28];
    const float* g1bi = (const float*)d_in[29];
    const float* g1bh = (const float*)d_in[30];
    const float* outw = (const float*)d_in[31];
    const float* outb = (const float*)d_in[32];
    float* out = (float*)d_out;

    float* pack = (float*)d_ws;           // 2*18*66*66*2 = 313632 floats
    float* gi0  = pack + 313632;          // 16384*48    = 786432 floats

    repack_kernel<<<(2 * NPOS * W66 * W66 + 255) / 256, 256, 0, stream>>>(
        c0w1r, c0w1i, c0w2r, c0w2i, c1w1r, c1w1i, c1w2r, c1w2i, pack);

    hipFuncSetAttribute(reinterpret_cast<const void*>(fno_kernel),
                        hipFuncAttributeMaxDynamicSharedMemorySize, 131072);
    size_t lds = (size_t)(SPB * FEAT * 3 + 1296 * 2 + 36 + SPB * W66 * 2) * sizeof(float);
    fno_kernel<<<NSAMP / SPB, NTH, lds, stream>>>(
        X, p_w, p_b, pack,
        m0aw, m0ab, m0bw, m0bb,
        m1aw, m1ab, m1bw, m1bb,
        w0w, w0b, w1w, w1b,
        g0wi, g0bi, gi0);

    gru_kernel<<<64, 64, 0, stream>>>(gi0, g0wh, g0bh, g1wi, g1wh, g1bi, g1bh, outw, outb, out);
}

// Round 2
// 5452.464 us; speedup vs baseline: 2.2050x; 2.2050x over previous
//
#include <hip/hip_runtime.h>

#define NTH 320          // 5 waves; >= 264 channel-units -> no double-duty straggler
#define SPB 4            // samples per block
#define W66 66
#define PIX36 36
#define NPOS 18          // kx in 0..5, ky in 0..2
#define FEAT 2376        // 66*36
#define TT 256
#define NSAMP 16384
#define CHU (SPB * W66)  // 264 channel units

// ws float offsets
#define PACK_FLOATS 313632            // 2*18*66*66*2
#define F2_OFF   PACK_FLOATS          // 648 float2 = 1296 floats
#define G2_OFF   (F2_OFF + 1296)      // 648 float2 = 1296 floats
#define FS_OFF   (G2_OFF + 1296)      // 18 float2 = 36 floats (pad to 72)
#define GI0_OFF  (FS_OFF + 72)

__constant__ float COS6[6] = {1.f, 0.5f, -0.5f, -1.f, -0.5f, 0.5f};
__constant__ float SIN6[6] = {0.f, 0.8660254037844386468f, 0.8660254037844386468f,
                              0.f, -0.8660254037844386468f, -0.8660254037844386468f};

__device__ __forceinline__ float gelu_f(float v) {
    return 0.5f * v * (1.f + erff(v * 0.70710678118654752440f));
}

// repack spectral weights into pack[L][p][i][o][{re,im}], p = kx*3+ky, kx 0..5
// and build DFT tables F2[p][k], G2[p][pix], Fsum2[p] in global ws.
extern "C" __global__ void repack_kernel(
    const float* __restrict__ w1r0, const float* __restrict__ w1i0,
    const float* __restrict__ w2r0, const float* __restrict__ w2i0,
    const float* __restrict__ w1r1, const float* __restrict__ w1i1,
    const float* __restrict__ w2r1, const float* __restrict__ w2i1,
    float* __restrict__ ws)
{
    int e = blockIdx.x * blockDim.x + threadIdx.x;
    const int TOT = 2 * NPOS * W66 * W66;
    if (e < TOT) {
        int L = e / (NPOS * W66 * W66);
        int r = e % (NPOS * W66 * W66);
        int p = r / (W66 * W66);
        int io = r % (W66 * W66);
        int i = io / W66, o = io % W66;
        int kx = p / 3, ky = p % 3;
        const float *wr, *wi;
        int kxw;
        if (L == 0) { if (kx < 3) { wr = w1r0; wi = w1i0; kxw = kx; } else { wr = w2r0; wi = w2i0; kxw = kx - 3; } }
        else        { if (kx < 3) { wr = w1r1; wi = w1i1; kxw = kx; } else { wr = w2r1; wi = w2i1; kxw = kx - 3; } }
        int src = ((i * W66 + o) * 3 + kxw) * 3 + ky;
        ws[(size_t)e * 2 + 0] = wr[src];
        ws[(size_t)e * 2 + 1] = wi[src];
    }
    if (e < NPOS * PIX36) {       // F2 and G2 tables
        int p = e / PIX36, k = e % PIX36;
        int kx = p / 3, ky = p % 3;
        int px = k / 6, py = k % 6;
        int m6 = (kx * px + ky * py) % 6;
        // forward: coeff on a_pix for (Re, Im) of xft[p]
        ws[F2_OFF + 2 * e + 0] = COS6[m6];
        ws[F2_OFF + 2 * e + 1] = -SIN6[m6];
        // inverse: coeff on (Re, Im) of oft[p] for pixel k
        float ck = (ky == 0) ? (1.f / 36.f) : (1.f / 18.f);
        ws[G2_OFF + 2 * e + 0] = ck * COS6[m6];
        ws[G2_OFF + 2 * e + 1] = -ck * SIN6[m6];
    }
    if (e < NPOS) {               // Fsum2[p] = sum_k F2[p][k]
        int kx = e / 3, ky = e % 3;
        float sr = 0.f, si = 0.f;
        for (int k = 0; k < PIX36; ++k) {
            int m6 = (kx * (k / 6) + ky * (k % 6)) % 6;
            sr += COS6[m6]; si -= SIN6[m6];
        }
        ws[FS_OFF + 2 * e + 0] = sr;
        ws[FS_OFF + 2 * e + 1] = si;
    }
}

extern "C" __global__ void __launch_bounds__(NTH, 2)
fno_kernel(const float* __restrict__ X, const float* __restrict__ p_w,
           const float* __restrict__ p_b, const float* __restrict__ ws,
           const float* __restrict__ m0aw, const float* __restrict__ m0ab,
           const float* __restrict__ m0bw, const float* __restrict__ m0bb,
           const float* __restrict__ m1aw, const float* __restrict__ m1ab,
           const float* __restrict__ m1bw, const float* __restrict__ m1bb,
           const float* __restrict__ w0w, const float* __restrict__ w0b,
           const float* __restrict__ w1w, const float* __restrict__ w1b,
           const float* __restrict__ gwi, const float* __restrict__ gbi,
           float* __restrict__ gi0out)
{
    extern __shared__ float sm[];
    float* A  = sm;                 // [s][pix][w]  h / skip (9504)
    float* Bb = A + SPB * FEAT;     // [s][j][w] xft -> [s][pix][o] spatial/t (9504)
    float* mv = Bb + SPB * FEAT;    // 264
    float* rv = mv + CHU;           // 264

    const float2* F2  = (const float2*)(ws + F2_OFF);   // [p][k]
    const float2* G2  = (const float2*)(ws + G2_OFF);   // [p][pix]
    const float2* FS2 = (const float2*)(ws + FS_OFF);   // [p]

    const int tid = threadIdx.x;
    const int n0 = blockIdx.x * SPB;

    // ---- embed: h = [x, gx, gy] @ p_w + p_b ----
    for (int e = tid; e < SPB * FEAT; e += NTH) {
        int s = e & 3, r = e >> 2;
        int w = r % W66, pix = r / W66;
        int px = pix / 6, py = pix % 6;
        float xv = X[(size_t)(n0 + s) * 36 + pix] + 0.01f;
        A[(s * PIX36 + pix) * W66 + w] =
            xv * p_w[w] + (px * 0.2f) * p_w[66 + w] + (py * 0.2f) * p_w[132 + w] + p_b[w];
    }
    __syncthreads();

    for (int L = 0; L < 2; ++L) {
        const float* maw = L ? m1aw : m0aw;
        const float* mab = L ? m1ab : m0ab;
        const float* mbw = L ? m1bw : m0bw;
        const float* mbb = L ? m1bb : m0bb;
        const float* skw = L ? w1w : w0w;
        const float* skb = L ? w1b : w0b;
        const float2* packF2 = ((const float2*)ws) + (size_t)L * NPOS * W66 * W66;

        // ---- instance-norm stats of A ----
        for (int c = tid; c < CHU; c += NTH) {
            int s = c & 3, ch = c >> 2;
            float smm = 0.f, sq = 0.f;
            #pragma unroll
            for (int pix = 0; pix < 36; ++pix) {
                float v = A[(s * PIX36 + pix) * W66 + ch];
                smm += v; sq = fmaf(v, v, sq);
            }
            float m = smm * (1.f / 36.f);
            float var = sq * (1.f / 36.f) - m * m;
            mv[c] = m; rv[c] = rsqrtf(var + 1e-5f);
        }
        __syncthreads();

        // ---- forward DFT (norm folded): A -> Bb [s][j=2p+c][w] ----
        for (int c = tid; c < CHU; c += NTH) {
            int s = c & 3, w = c >> 2;
            float ar[36];
            #pragma unroll
            for (int pix = 0; pix < 36; ++pix) ar[pix] = A[(s * PIX36 + pix) * W66 + w];
            float m = mv[c], rs = rv[c];
            #pragma unroll 1
            for (int p = 0; p < NPOS; ++p) {
                const float2* fr = F2 + p * 36;
                float s0 = 0.f, s1 = 0.f, t0 = 0.f, t1 = 0.f;
                #pragma unroll
                for (int k = 0; k < 36; k += 2) {
                    float2 f0 = fr[k], f1 = fr[k + 1];
                    s0 = fmaf(ar[k], f0.x, s0);
                    t0 = fmaf(ar[k], f0.y, t0);
                    s1 = fmaf(ar[k + 1], f1.x, s1);
                    t1 = fmaf(ar[k + 1], f1.y, t1);
                }
                float2 fs = FS2[p];
                Bb[(s * 36 + 2 * p) * W66 + w]     = rs * ((s0 + s1) - m * fs.x);
                Bb[(s * 36 + 2 * p + 1) * W66 + w] = rs * ((t0 + t1) - m * fs.y);
            }
        }
        __syncthreads();

        // ---- fused channel-mix + inverse DFT: Bb(xft) -> sp[36] regs ----
        {
            float sp[36];
            int c = tid;
            if (c < CHU) {
                int s = c & 3, o = c >> 2;
                #pragma unroll
                for (int pix = 0; pix < 36; ++pix) sp[pix] = 0.f;
                #pragma unroll 1
                for (int p = 0; p < NPOS; ++p) {
                    const float* bR = Bb + (s * 36 + 2 * p) * W66;
                    const float* bI = bR + W66;
                    const float2* wp = packF2 + (size_t)(p * W66) * W66 + o;
                    float ar0 = 0.f, ai0 = 0.f, ar1 = 0.f, ai1 = 0.f;
                    #pragma unroll 1
                    for (int i = 0; i < W66; i += 2) {
                        float xr0 = bR[i], xi0 = bI[i];
                        float2 wv0 = wp[(size_t)i * W66];
                        ar0 = fmaf(xr0, wv0.x, ar0); ar0 = fmaf(xi0, -wv0.y, ar0);
                        ai0 = fmaf(xr0, wv0.y, ai0); ai0 = fmaf(xi0, wv0.x, ai0);
                        float xr1 = bR[i + 1], xi1 = bI[i + 1];
                        float2 wv1 = wp[(size_t)(i + 1) * W66];
                        ar1 = fmaf(xr1, wv1.x, ar1); ar1 = fmaf(xi1, -wv1.y, ar1);
                        ai1 = fmaf(xr1, wv1.y, ai1); ai1 = fmaf(xi1, wv1.x, ai1);
                    }
                    float orr = ar0 + ar1, oii = ai0 + ai1;
                    const float2* gp = G2 + p * 36;
                    #pragma unroll
                    for (int pix = 0; pix < 36; ++pix) {
                        float2 g = gp[pix];
                        sp[pix] = fmaf(g.x, orr, sp[pix]);
                        sp[pix] = fmaf(g.y, oii, sp[pix]);
                    }
                }
            }
            __syncthreads();     // all xft reads complete
            if (c < CHU) {
                int s = c & 3, o = c >> 2;
                #pragma unroll
                for (int pix = 0; pix < 36; ++pix) Bb[(s * PIX36 + pix) * W66 + o] = sp[pix];
            }
            __syncthreads();
        }

        // ---- instance-norm stats of spectral output ----
        for (int c = tid; c < CHU; c += NTH) {
            int s = c & 3, ch = c >> 2;
            float smm = 0.f, sq = 0.f;
            #pragma unroll
            for (int pix = 0; pix < 36; ++pix) {
                float v = Bb[(s * PIX36 + pix) * W66 + ch];
                smm += v; sq = fmaf(v, v, sq);
            }
            float m = smm * (1.f / 36.f);
            float var = sq * (1.f / 36.f) - m * m;
            mv[c] = m; rv[c] = rsqrtf(var + 1e-5f);
        }
        __syncthreads();

        // ---- MLP conv1 (norm folded) -> t regs -> Bb in place ----
        {
            float acc[36];
            int c = tid;
            if (c < CHU) {
                int s = c & 3, o = c >> 2;
                #pragma unroll
                for (int pix = 0; pix < 36; ++pix) acc[pix] = 0.f;
                float corr = 0.f;
                #pragma unroll 1
                for (int i = 0; i < W66; ++i) {
                    float wv2 = maw[o * W66 + i] * rv[(i << 2) | s];
                    corr = fmaf(wv2, mv[(i << 2) | s], corr);
                    const float* brow = Bb + s * FEAT + i;
                    #pragma unroll
                    for (int pix = 0; pix < 36; ++pix)
                        acc[pix] = fmaf(wv2, brow[pix * W66], acc[pix]);
                }
                float bias = mab[o] - corr;
                #pragma unroll
                for (int pix = 0; pix < 36; ++pix) acc[pix] = gelu_f(acc[pix] + bias);
            }
            __syncthreads();     // all normalized-x reads complete
            if (c < CHU) {
                int s = c & 3, o = c >> 2;
                #pragma unroll
                for (int pix = 0; pix < 36; ++pix) Bb[(s * PIX36 + pix) * W66 + o] = acc[pix];
            }
            __syncthreads();
        }

        // ---- MLP conv2 + skip conv + gelu -> A ----
        {
            float ov[36];
            int c = tid;
            if (c < CHU) {
                int s = c & 3, o = c >> 2;
                float by = mbb[o], bs2 = skb[o];
                float sk[36];
                #pragma unroll
                for (int pix = 0; pix < 36; ++pix) { ov[pix] = by; sk[pix] = bs2; }
                #pragma unroll 1
                for (int i = 0; i < W66; ++i) {
                    float wy = mbw[o * W66 + i];
                    float wsk = skw[o * W66 + i];
                    const float* trow = Bb + s * FEAT + i;
                    const float* arow = A + s * FEAT + i;
                    #pragma unroll
                    for (int pix = 0; pix < 36; ++pix) {
                        ov[pix] = fmaf(wy, trow[pix * W66], ov[pix]);
                        sk[pix] = fmaf(wsk, arow[pix * W66], sk[pix]);
                    }
                }
                #pragma unroll
                for (int pix = 0; pix < 36; ++pix) ov[pix] = gelu_f(ov[pix] + sk[pix]);
            }
            __syncthreads();     // all skip reads of A complete
            if (c < CHU) {
                int s = c & 3, o = c >> 2;
                #pragma unroll
                for (int pix = 0; pix < 36; ++pix) A[(s * PIX36 + pix) * W66 + o] = ov[pix];
            }
            __syncthreads();
        }
    }

    // ---- epilogue: gi0 = feats @ Wi0^T + bi0 (feat index = w*36 + pix) ----
    for (int c = tid; c < SPB * 48; c += NTH) {
        int s = c & 3, g = c >> 2;
        const float* wrow = gwi + (size_t)g * FEAT;
        float a0 = 0.f, a1 = 0.f, a2 = 0.f, a3 = 0.f;
        #pragma unroll 1
        for (int w = 0; w < W66; ++w) {
            const float* arow = A + s * FEAT + w;
            const float* wr = wrow + w * 36;
            #pragma unroll
            for (int pix = 0; pix < 36; pix += 4) {
                float4 wq = *(const float4*)(wr + pix);
                a0 = fmaf(arow[(pix + 0) * W66], wq.x, a0);
                a1 = fmaf(arow[(pix + 1) * W66], wq.y, a1);
                a2 = fmaf(arow[(pix + 2) * W66], wq.z, a2);
                a3 = fmaf(arow[(pix + 3) * W66], wq.w, a3);
            }
        }
        gi0out[(size_t)(n0 + s) * 48 + g] = ((a0 + a1) + (a2 + a3)) + gbi[g];
    }
}

// fused GRU0 + GRU1 + output linear; one block per batch element, one wave.
extern "C" __global__ void __launch_bounds__(64, 1)
gru_kernel(const float* __restrict__ gi0, const float* __restrict__ wh0,
           const float* __restrict__ bh0, const float* __restrict__ wi1,
           const float* __restrict__ wh1, const float* __restrict__ bi1,
           const float* __restrict__ bh1, const float* __restrict__ outw,
           const float* __restrict__ outb, float* __restrict__ y)
{
    int b = blockIdx.x;
    int g = threadIdx.x;
    int gw = (g < 48) ? g : 0;
    float rwh0[16], rwi1[16], rwh1[16];
    #pragma unroll
    for (int j = 0; j < 16; ++j) {
        rwh0[j] = wh0[gw * 16 + j];
        rwi1[j] = wi1[gw * 16 + j];
        rwh1[j] = wh1[gw * 16 + j];
    }
    float vbh0 = bh0[gw], vbi1 = bi1[gw], vbh1 = bh1[gw];
    float vow = (g < 16) ? outw[g] : 0.f;
    float ob = outb[0];
    float h0 = 0.f, h1 = 0.f;
    int base = b * TT;
    int j = g & 15;
    float cur = (g < 48) ? gi0[(size_t)base * 48 + g] : 0.f;
    for (int t = 0; t < TT; ++t) {
        int tn = (t + 1 < TT) ? t + 1 : t;
        float nxt = (g < 48) ? gi0[((size_t)base + tn) * 48 + g] : 0.f;
        float gh0 = vbh0;
        #pragma unroll
        for (int k = 0; k < 16; ++k) gh0 = fmaf(rwh0[k], __shfl(h0, k), gh0);
        float gir = __shfl(cur, j), giz = __shfl(cur, 16 + j), gin = __shfl(cur, 32 + j);
        float ghr = __shfl(gh0, j), ghz = __shfl(gh0, 16 + j), ghn = __shfl(gh0, 32 + j);
        float r = 1.f / (1.f + expf(-(gir + ghr)));
        float z = 1.f / (1.f + expf(-(giz + ghz)));
        float n = tanhf(gin + r * ghn);
        h0 = (1.f - z) * n + z * h0;
        float gi1 = vbi1, gh1 = vbh1;
        #pragma unroll
        for (int k = 0; k < 16; ++k) {
            gi1 = fmaf(rwi1[k], __shfl(h0, k), gi1);
            gh1 = fmaf(rwh1[k], __shfl(h1, k), gh1);
        }
        float air = __shfl(gi1, j) + __shfl(gh1, j);
        float aiz = __shfl(gi1, 16 + j) + __shfl(gh1, 16 + j);
        float r1 = 1.f / (1.f + expf(-air));
        float z1 = 1.f / (1.f + expf(-aiz));
        float n1 = tanhf(__shfl(gi1, 32 + j) + r1 * __shfl(gh1, 32 + j));
        h1 = (1.f - z1) * n1 + z1 * h1;
        float v = h1 * vow;
        #pragma unroll
        for (int off = 32; off; off >>= 1) v += __shfl_xor(v, off);
        if (g == 0) y[base + t] = v + ob;
        cur = nxt;
    }
}

extern "C" void kernel_launch(void* const* d_in, const int* in_sizes, int n_in,
                              void* d_out, int out_size, void* d_ws, size_t ws_size,
                              hipStream_t stream) {
    const float* X    = (const float*)d_in[0];
    const float* p_w  = (const float*)d_in[1];
    const float* p_b  = (const float*)d_in[2];
    const float* c0w1r = (const float*)d_in[3];
    const float* c0w1i = (const float*)d_in[4];
    const float* c0w2r = (const float*)d_in[5];
    const float* c0w2i = (const float*)d_in[6];
    const float* c1w1r = (const float*)d_in[7];
    const float* c1w1i = (const float*)d_in[8];
    const float* c1w2r = (const float*)d_in[9];
    const float* c1w2i = (const float*)d_in[10];
    const float* m0aw = (const float*)d_in[11];
    const float* m0ab = (const float*)d_in[12];
    const float* m0bw = (const float*)d_in[13];
    const float* m0bb = (const float*)d_in[14];
    const float* m1aw = (const float*)d_in[15];
    const float* m1ab = (const float*)d_in[16];
    const float* m1bw = (const float*)d_in[17];
    const float* m1bb = (const float*)d_in[18];
    const float* w0w  = (const float*)d_in[19];
    const float* w0b  = (const float*)d_in[20];
    const float* w1w  = (const float*)d_in[21];
    const float* w1b  = (const float*)d_in[22];
    const float* g0wi = (const float*)d_in[23];
    const float* g0wh = (const float*)d_in[24];
    const float* g0bi = (const float*)d_in[25];
    const float* g0bh = (const float*)d_in[26];
    const float* g1wi = (const float*)d_in[27];
    const float* g1wh = (const float*)d_in[28];
    const float* g1bi = (const float*)d_in[29];
    const float* g1bh = (const float*)d_in[30];
    const float* outw = (const float*)d_in[31];
    const float* outb = (const float*)d_in[32];
    float* out = (float*)d_out;

    float* ws   = (float*)d_ws;
    float* gi0  = ws + GI0_OFF;

    repack_kernel<<<(2 * NPOS * W66 * W66 + 255) / 256, 256, 0, stream>>>(
        c0w1r, c0w1i, c0w2r, c0w2i, c1w1r, c1w1i, c1w2r, c1w2i, ws);

    hipFuncSetAttribute(reinterpret_cast<const void*>(fno_kernel),
                        hipFuncAttributeMaxDynamicSharedMemorySize, 131072);
    size_t lds = (size_t)(SPB * FEAT * 2 + CHU * 2) * sizeof(float);
    fno_kernel<<<NSAMP / SPB, NTH, lds, stream>>>(
        X, p_w, p_b, ws,
        m0aw, m0ab, m0bw, m0bb,
        m1aw, m1ab, m1bw, m1bb,
        w0w, w0b, w1w, w1b,
        g0wi, g0bi, gi0);

    gru_kernel<<<64, 64, 0, stream>>>(gi0, g0wh, g0bh, g1wi, g1wh, g1bi, g1bh, outw, outb, out);
}

// Round 3
// 3918.873 us; speedup vs baseline: 3.0679x; 1.3913x over previous
//
#include <hip/hip_runtime.h>

#define NTH 640          // 10 waves/CU, 1 block/CU
#define SPB 8            // samples per block
#define W66 66
#define PIX36 36
#define NPOS 18          // kx in 0..5, ky in 0..2
#define FEAT 2376        // 66*36
#define TT 256
#define NSAMP 16384
#define CHU (SPB * W66)  // 528 channel units

// ws float offsets
#define PACK_FLOATS (2 * NPOS * W66 * W66)    // 313632
#define F2_OFF   PACK_FLOATS                  // 648 float2
#define G2_OFF   (F2_OFF + 1296)              // 648 float2
#define FS_OFF   (G2_OFF + 1296)              // 18 float2 (pad to 72)
#define GI0_OFF  (FS_OFF + 72)

__constant__ float COS6[6] = {1.f, 0.5f, -0.5f, -1.f, -0.5f, 0.5f};
__constant__ float SIN6[6] = {0.f, 0.8660254037844386468f, 0.8660254037844386468f,
                              0.f, -0.8660254037844386468f, -0.8660254037844386468f};

__device__ __forceinline__ float gelu_f(float v) {
    return 0.5f * v * (1.f + erff(v * 0.70710678118654752440f));
}

// repack spectral weights into pack[L][p][i][o][{re,im}], p = kx*3+ky, kx 0..5
// and build DFT tables F2[p][k], G2[p][pix], Fsum2[p] in global ws.
extern "C" __global__ void repack_kernel(
    const float* __restrict__ w1r0, const float* __restrict__ w1i0,
    const float* __restrict__ w2r0, const float* __restrict__ w2i0,
    const float* __restrict__ w1r1, const float* __restrict__ w1i1,
    const float* __restrict__ w2r1, const float* __restrict__ w2i1,
    float* __restrict__ ws)
{
    int e = blockIdx.x * blockDim.x + threadIdx.x;
    const int TOT = 2 * NPOS * W66 * W66;
    if (e < TOT) {
        int L = e / (NPOS * W66 * W66);
        int r = e % (NPOS * W66 * W66);
        int p = r / (W66 * W66);
        int io = r % (W66 * W66);
        int i = io / W66, o = io % W66;
        int kx = p / 3, ky = p % 3;
        const float *wr, *wi;
        int kxw;
        if (L == 0) { if (kx < 3) { wr = w1r0; wi = w1i0; kxw = kx; } else { wr = w2r0; wi = w2i0; kxw = kx - 3; } }
        else        { if (kx < 3) { wr = w1r1; wi = w1i1; kxw = kx; } else { wr = w2r1; wi = w2i1; kxw = kx - 3; } }
        int src = ((i * W66 + o) * 3 + kxw) * 3 + ky;
        ws[(size_t)e * 2 + 0] = wr[src];
        ws[(size_t)e * 2 + 1] = wi[src];
    }
    if (e < NPOS * PIX36) {       // F2 and G2 tables
        int p = e / PIX36, k = e % PIX36;
        int kx = p / 3, ky = p % 3;
        int px = k / 6, py = k % 6;
        int m6 = (kx * px + ky * py) % 6;
        ws[F2_OFF + 2 * e + 0] = COS6[m6];
        ws[F2_OFF + 2 * e + 1] = -SIN6[m6];
        float ck = (ky == 0) ? (1.f / 36.f) : (1.f / 18.f);
        ws[G2_OFF + 2 * e + 0] = ck * COS6[m6];
        ws[G2_OFF + 2 * e + 1] = -ck * SIN6[m6];
    }
    if (e < NPOS) {               // Fsum2[p]
        int kx = e / 3, ky = e % 3;
        float sr = 0.f, si = 0.f;
        for (int k = 0; k < PIX36; ++k) {
            int m6 = (kx * (k / 6) + ky * (k % 6)) % 6;
            sr += COS6[m6]; si -= SIN6[m6];
        }
        ws[FS_OFF + 2 * e + 0] = sr;
        ws[FS_OFF + 2 * e + 1] = si;
    }
}

extern "C" __global__ void __launch_bounds__(NTH, 3)
fno_kernel(const float* __restrict__ X, const float* __restrict__ p_w,
           const float* __restrict__ p_b, const float* __restrict__ ws,
           const float* __restrict__ m0aw, const float* __restrict__ m0ab,
           const float* __restrict__ m0bw, const float* __restrict__ m0bb,
           const float* __restrict__ m1aw, const float* __restrict__ m1ab,
           const float* __restrict__ m1bw, const float* __restrict__ m1bb,
           const float* __restrict__ w0w, const float* __restrict__ w0b,
           const float* __restrict__ w1w, const float* __restrict__ w1b,
           const float* __restrict__ gwi, const float* __restrict__ gbi,
           float* __restrict__ gi0out)
{
    extern __shared__ float sm[];
    float* A  = sm;                 // [s][pix][ch] skip (19008)
    float* Bb = A + SPB * FEAT;     // xft/oft as float2 [s][p][ch] OR spatial/t [s][pix][ch] (19008)
    float* mv = Bb + SPB * FEAT;    // 528
    float* rv = mv + CHU;           // 528

    const float2* F2  = (const float2*)(ws + F2_OFF);
    const float2* G2  = (const float2*)(ws + G2_OFF);
    const float2* FS2 = (const float2*)(ws + FS_OFF);

    const int tid = threadIdx.x;
    const int n0 = blockIdx.x * SPB;
    const int s  = tid & 7, ch = tid >> 3;   // valid when act
    const bool act = tid < CHU;

    float h[36], hm, hrs;

    // ---- embed + stats (in-reg) + A write ----
    if (act) {
        float pw0 = p_w[ch], pw1 = p_w[66 + ch], pw2 = p_w[132 + ch], pb = p_b[ch];
        const float4* xr = (const float4*)(X + (size_t)(n0 + s) * 36);
        float sum = 0.f, sq = 0.f;
        #pragma unroll
        for (int q = 0; q < 9; ++q) {
            float4 xv = xr[q];
            float vv[4] = {xv.x, xv.y, xv.z, xv.w};
            #pragma unroll
            for (int e = 0; e < 4; ++e) {
                const int pix = q * 4 + e;
                const int px = pix / 6, py = pix % 6;
                float v = fmaf(vv[e] + 0.01f, pw0,
                          fmaf(px * 0.2f, pw1, fmaf(py * 0.2f, pw2, pb)));
                h[pix] = v; sum += v; sq = fmaf(v, v, sq);
            }
        }
        float m = sum * (1.f / 36.f);
        hm = m; hrs = rsqrtf(sq * (1.f / 36.f) - m * m + 1e-5f);
        #pragma unroll
        for (int pix = 0; pix < 36; ++pix) A[(s * 36 + pix) * 66 + ch] = h[pix];
    }
    // embed A-writes: first cross-thread read is in C2, many barriers away.

    for (int L = 0; L < 2; ++L) {
        const float* maw = L ? m1aw : m0aw;
        const float* mab = L ? m1ab : m0ab;
        const float* mbw = L ? m1bw : m0bw;
        const float* mbb = L ? m1bb : m0bb;
        const float* skw = L ? w1w : w0w;
        const float* skb = L ? w1b : w0b;

        // ---- F: forward DFT from h regs (norm folded) -> Bb xft [s][p][ch] float2 ----
        if (act) {
            float2* outp = (float2*)Bb + s * (18 * 66) + ch;
            #pragma unroll 1
            for (int p = 0; p < 18; ++p) {
                const float2* fr = F2 + p * 36;
                float sr = 0.f, si = 0.f, sr1 = 0.f, si1 = 0.f;
                #pragma unroll
                for (int k = 0; k < 36; k += 2) {
                    float2 f0 = fr[k], f1 = fr[k + 1];
                    sr  = fmaf(h[k],     f0.x, sr);   si  = fmaf(h[k],     f0.y, si);
                    sr1 = fmaf(h[k + 1], f1.x, sr1);  si1 = fmaf(h[k + 1], f1.y, si1);
                }
                float2 fs = FS2[p];
                float2 o2;
                o2.x = hrs * ((sr + sr1) - hm * fs.x);
                o2.y = hrs * ((si + si1) - hm * fs.y);
                outp[p * 66] = o2;
            }
        }
        __syncthreads();  // B1: xft complete

        // ---- M: channel mix, units (p,o), all 8 samples per thread ----
        {
            const float2* packL = ((const float2*)ws) + (size_t)L * NPOS * W66 * W66;
            const int u0 = tid, u1t = tid + NTH;
            const bool a1 = (u1t < NPOS * W66);
            const int u1 = a1 ? u1t : u0;
            const int p0 = u0 / 66, o0 = u0 - p0 * 66;
            const int p1 = u1 / 66, o1 = u1 - p1 * 66;
            float ar0[8], ai0[8], ar1[8], ai1[8];
            #pragma unroll
            for (int q = 0; q < 8; ++q) { ar0[q] = 0.f; ai0[q] = 0.f; ar1[q] = 0.f; ai1[q] = 0.f; }
            const float2* wp0 = packL + (size_t)(p0 * 66) * 66 + o0;
            const float2* wp1 = packL + (size_t)(p1 * 66) * 66 + o1;
            const float2* xb0 = (const float2*)Bb + p0 * 66;
            const float2* xb1 = (const float2*)Bb + p1 * 66;
            #pragma unroll 2
            for (int i = 0; i < 66; ++i) {
                float2 w0 = wp0[(size_t)i * 66];
                float2 w1 = wp1[(size_t)i * 66];
                #pragma unroll
                for (int q = 0; q < 8; ++q) {
                    float2 x0 = xb0[q * 1188 + i];
                    ar0[q] = fmaf(x0.x, w0.x, ar0[q]);
                    ar0[q] = fmaf(x0.y, -w0.y, ar0[q]);
                    ai0[q] = fmaf(x0.x, w0.y, ai0[q]);
                    ai0[q] = fmaf(x0.y, w0.x, ai0[q]);
                    float2 x1 = xb1[q * 1188 + i];
                    ar1[q] = fmaf(x1.x, w1.x, ar1[q]);
                    ar1[q] = fmaf(x1.y, -w1.y, ar1[q]);
                    ai1[q] = fmaf(x1.x, w1.y, ai1[q]);
                    ai1[q] = fmaf(x1.y, w1.x, ai1[q]);
                }
            }
            __syncthreads();  // B2: all xft reads done
            float2* ob = (float2*)Bb;
            #pragma unroll
            for (int q = 0; q < 8; ++q)
                ob[q * 1188 + p0 * 66 + o0] = make_float2(ar0[q], ai0[q]);
            if (a1) {
                #pragma unroll
                for (int q = 0; q < 8; ++q)
                    ob[q * 1188 + p1 * 66 + o1] = make_float2(ar1[q], ai1[q]);
            }
        }
        __syncthreads();  // B3: oft complete

        // ---- I: inverse DFT + stats (in-reg) ----
        float sp[36];
        float m2 = 0.f, rs2 = 0.f;
        if (act) {
            #pragma unroll
            for (int pix = 0; pix < 36; ++pix) sp[pix] = 0.f;
            const float2* col = (const float2*)Bb + s * 1188 + ch;
            #pragma unroll 1
            for (int p = 0; p < 18; ++p) {
                float2 ovv = col[p * 66];
                const float2* gp = G2 + p * 36;
                #pragma unroll
                for (int pix = 0; pix < 36; ++pix) {
                    float2 g = gp[pix];
                    sp[pix] = fmaf(g.x, ovv.x, sp[pix]);
                    sp[pix] = fmaf(g.y, ovv.y, sp[pix]);
                }
            }
            float sum = 0.f, sq = 0.f;
            #pragma unroll
            for (int pix = 0; pix < 36; ++pix) { sum += sp[pix]; sq = fmaf(sp[pix], sp[pix], sq); }
            float m = sum * (1.f / 36.f);
            m2 = m; rs2 = rsqrtf(sq * (1.f / 36.f) - m * m + 1e-5f);
        }
        __syncthreads();  // B4: all oft reads done
        if (act) {
            #pragma unroll
            for (int pix = 0; pix < 36; ++pix) Bb[(s * 36 + pix) * 66 + ch] = sp[pix];
            mv[tid] = m2; rv[tid] = rs2;
        }
        __syncthreads();  // B5: spatial + stats visible

        // ---- C1: conv1 (norm folded) + gelu ----
        float tt[36];
        if (act) {
            #pragma unroll
            for (int pix = 0; pix < 36; ++pix) tt[pix] = 0.f;
            float corr = 0.f;
            #pragma unroll 1
            for (int i = 0; i < 66; ++i) {
                float wvv = maw[ch * 66 + i] * rv[(i << 3) | s];
                corr = fmaf(wvv, mv[(i << 3) | s], corr);
                const float* brow = Bb + s * FEAT + i;
                #pragma unroll
                for (int pix = 0; pix < 36; ++pix)
                    tt[pix] = fmaf(wvv, brow[pix * 66], tt[pix]);
            }
            float bias = mab[ch] - corr;
            #pragma unroll
            for (int pix = 0; pix < 36; ++pix) tt[pix] = gelu_f(tt[pix] + bias);
        }
        __syncthreads();  // B6: all spatial reads done
        if (act) {
            #pragma unroll
            for (int pix = 0; pix < 36; ++pix) Bb[(s * 36 + pix) * 66 + ch] = tt[pix];
        }
        __syncthreads();  // B7: t visible

        // ---- C2: conv2 + skip conv + gelu + stats (in-reg) -> h regs + A ----
        if (act) {
            float ov[36], sk[36];
            float by = mbb[ch], bs = skb[ch];
            #pragma unroll
            for (int pix = 0; pix < 36; ++pix) { ov[pix] = by; sk[pix] = bs; }
            #pragma unroll 1
            for (int i = 0; i < 66; ++i) {
                float wy = mbw[ch * 66 + i];
                float wk = skw[ch * 66 + i];
                const float* trow = Bb + s * FEAT + i;
                const float* arow = A + s * FEAT + i;
                #pragma unroll
                for (int pix = 0; pix < 36; ++pix) {
                    ov[pix] = fmaf(wy, trow[pix * 66], ov[pix]);
                    sk[pix] = fmaf(wk, arow[pix * 66], sk[pix]);
                }
            }
            float sum = 0.f, sq = 0.f;
            #pragma unroll
            for (int pix = 0; pix < 36; ++pix) {
                float v = gelu_f(ov[pix] + sk[pix]);
                h[pix] = v; sum += v; sq = fmaf(v, v, sq);
            }
            float m = sum * (1.f / 36.f);
            hm = m; hrs = rsqrtf(sq * (1.f / 36.f) - m * m + 1e-5f);
        }
        __syncthreads();  // B8: all t/A reads done
        if (act) {
            #pragma unroll
            for (int pix = 0; pix < 36; ++pix) A[(s * 36 + pix) * 66 + ch] = h[pix];
        }
        // next F writes Bb only; first cross-thread A read is next layer's C2 (after B1..B7)
    }

    __syncthreads();  // B9: final A visible
    // ---- epilogue: gi0 = feats @ Wi0^T + bi0; units (third, s, g), partials in Bb ----
    #pragma unroll
    for (int k = 0; k < 2; ++k) {
        int u = tid + k * NTH;
        if (u < 1152) {
            int third = u / 384, sg = u - third * 384;
            int es = sg & 7, g = sg >> 3;
            const float* wrow = gwi + (size_t)g * FEAT + third * (22 * 36);
            const float* abase = A + es * FEAT + third * 22;
            float a0 = 0.f, a1 = 0.f, a2 = 0.f, a3 = 0.f;
            #pragma unroll 1
            for (int w = 0; w < 22; ++w) {
                const float* arow = abase + w;
                const float* wr = wrow + w * 36;
                #pragma unroll
                for (int pix = 0; pix < 36; pix += 4) {
                    float4 wq = *(const float4*)(wr + pix);
                    a0 = fmaf(arow[(pix + 0) * 66], wq.x, a0);
                    a1 = fmaf(arow[(pix + 1) * 66], wq.y, a1);
                    a2 = fmaf(arow[(pix + 2) * 66], wq.z, a2);
                    a3 = fmaf(arow[(pix + 3) * 66], wq.w, a3);
                }
            }
            Bb[u] = (a0 + a1) + (a2 + a3);
        }
    }
    __syncthreads();  // B10: partials visible
    if (tid < 384) {
        int es = tid & 7, g = tid >> 3;
        gi0out[(size_t)(n0 + es) * 48 + g] = Bb[tid] + Bb[tid + 384] + Bb[tid + 768] + gbi[g];
    }
}

// fused GRU0 + GRU1 + output linear; one block per batch element, one wave.
extern "C" __global__ void __launch_bounds__(64, 1)
gru_kernel(const float* __restrict__ gi0, const float* __restrict__ wh0,
           const float* __restrict__ bh0, const float* __restrict__ wi1,
           const float* __restrict__ wh1, const float* __restrict__ bi1,
           const float* __restrict__ bh1, const float* __restrict__ outw,
           const float* __restrict__ outb, float* __restrict__ y)
{
    int b = blockIdx.x;
    int g = threadIdx.x;
    int gw = (g < 48) ? g : 0;
    float rwh0[16], rwi1[16], rwh1[16];
    #pragma unroll
    for (int j = 0; j < 16; ++j) {
        rwh0[j] = wh0[gw * 16 + j];
        rwi1[j] = wi1[gw * 16 + j];
        rwh1[j] = wh1[gw * 16 + j];
    }
    float vbh0 = bh0[gw], vbi1 = bi1[gw], vbh1 = bh1[gw];
    float vow = (g < 16) ? outw[g] : 0.f;
    float ob = outb[0];
    float h0 = 0.f, h1 = 0.f;
    int base = b * TT;
    int j = g & 15;
    float cur = (g < 48) ? gi0[(size_t)base * 48 + g] : 0.f;
    for (int t = 0; t < TT; ++t) {
        int tn = (t + 1 < TT) ? t + 1 : t;
        float nxt = (g < 48) ? gi0[((size_t)base + tn) * 48 + g] : 0.f;
        float gh0 = vbh0;
        #pragma unroll
        for (int k = 0; k < 16; ++k) gh0 = fmaf(rwh0[k], __shfl(h0, k), gh0);
        float gir = __shfl(cur, j), giz = __shfl(cur, 16 + j), gin = __shfl(cur, 32 + j);
        float ghr = __shfl(gh0, j), ghz = __shfl(gh0, 16 + j), ghn = __shfl(gh0, 32 + j);
        float r = 1.f / (1.f + expf(-(gir + ghr)));
        float z = 1.f / (1.f + expf(-(giz + ghz)));
        float n = tanhf(gin + r * ghn);
        h0 = (1.f - z) * n + z * h0;
        float gi1 = vbi1, gh1 = vbh1;
        #pragma unroll
        for (int k = 0; k < 16; ++k) {
            gi1 = fmaf(rwi1[k], __shfl(h0, k), gi1);
            gh1 = fmaf(rwh1[k], __shfl(h1, k), gh1);
        }
        float air = __shfl(gi1, j) + __shfl(gh1, j);
        float aiz = __shfl(gi1, 16 + j) + __shfl(gh1, 16 + j);
        float r1 = 1.f / (1.f + expf(-air));
        float z1 = 1.f / (1.f + expf(-aiz));
        float n1 = tanhf(__shfl(gi1, 32 + j) + r1 * __shfl(gh1, 32 + j));
        h1 = (1.f - z1) * n1 + z1 * h1;
        float v = h1 * vow;
        #pragma unroll
        for (int off = 32; off; off >>= 1) v += __shfl_xor(v, off);
        if (g == 0) y[base + t] = v + ob;
        cur = nxt;
    }
}

extern "C" void kernel_launch(void* const* d_in, const int* in_sizes, int n_in,
                              void* d_out, int out_size, void* d_ws, size_t ws_size,
                              hipStream_t stream) {
    const float* X    = (const float*)d_in[0];
    const float* p_w  = (const float*)d_in[1];
    const float* p_b  = (const float*)d_in[2];
    const float* c0w1r = (const float*)d_in[3];
    const float* c0w1i = (const float*)d_in[4];
    const float* c0w2r = (const float*)d_in[5];
    const float* c0w2i = (const float*)d_in[6];
    const float* c1w1r = (const float*)d_in[7];
    const float* c1w1i = (const float*)d_in[8];
    const float* c1w2r = (const float*)d_in[9];
    const float* c1w2i = (const float*)d_in[10];
    const float* m0aw = (const float*)d_in[11];
    const float* m0ab = (const float*)d_in[12];
    const float* m0bw = (const float*)d_in[13];
    const float* m0bb = (const float*)d_in[14];
    const float* m1aw = (const float*)d_in[15];
    const float* m1ab = (const float*)d_in[16];
    const float* m1bw = (const float*)d_in[17];
    const float* m1bb = (const float*)d_in[18];
    const float* w0w  = (const float*)d_in[19];
    const float* w0b  = (const float*)d_in[20];
    const float* w1w  = (const float*)d_in[21];
    const float* w1b  = (const float*)d_in[22];
    const float* g0wi = (const float*)d_in[23];
    const float* g0wh = (const float*)d_in[24];
    const float* g0bi = (const float*)d_in[25];
    const float* g0bh = (const float*)d_in[26];
    const float* g1wi = (const float*)d_in[27];
    const float* g1wh = (const float*)d_in[28];
    const float* g1bi = (const float*)d_in[29];
    const float* g1bh = (const float*)d_in[30];
    const float* outw = (const float*)d_in[31];
    const float* outb = (const float*)d_in[32];
    float* out = (float*)d_out;

    float* ws   = (float*)d_ws;
    float* gi0  = ws + GI0_OFF;

    repack_kernel<<<(2 * NPOS * W66 * W66 + 255) / 256, 256, 0, stream>>>(
        c0w1r, c0w1i, c0w2r, c0w2i, c1w1r, c1w1i, c1w2r, c1w2i, ws);

    size_t lds = (size_t)(SPB * FEAT * 2 + CHU * 2) * sizeof(float);  // 156288 B
    hipFuncSetAttribute(reinterpret_cast<const void*>(fno_kernel),
                        hipFuncAttributeMaxDynamicSharedMemorySize, (int)lds);
    fno_kernel<<<NSAMP / SPB, NTH, lds, stream>>>(
        X, p_w, p_b, ws,
        m0aw, m0ab, m0bw, m0bb,
        m1aw, m1ab, m1bw, m1bb,
        w0w, w0b, w1w, w1b,
        g0wi, g0bi, gi0);

    gru_kernel<<<64, 64, 0, stream>>>(gi0, g0wh, g0bh, g1wi, g1wh, g1bi, g1bh, outw, outb, out);
}